// Round 15
// baseline (39.112 us; speedup 1.0000x reference)
//
#include <hip/hip_runtime.h>

typedef short short8 __attribute__((ext_vector_type(8)));
typedef float f32x4 __attribute__((ext_vector_type(4)));

#define NB 8
#define NC 64
#define NN 16384
#define NO 64
#define SQRT13 3.605551275463989f

// ws layout (floats):
// [0, 4096)     : pp[b][c][8] = {a, bsh, cp0..cp5}              512*8
// [4096, 6144)  : WtB bf16[o][c] row-major (4096 ushort = 8KB)

__device__ __forceinline__ unsigned short f2bf(float f) {
    unsigned int u = __builtin_bit_cast(unsigned int, f);
    u += 0x7fffu + ((u >> 16) & 1u);   // RNE
    return (unsigned short)(u >> 16);
}

__device__ __forceinline__ unsigned int pack_bf2(float lo, float hi) {
    return (unsigned int)f2bf(lo) | ((unsigned int)f2bf(hi) << 16);
}

__device__ __forceinline__ float tanh13(float x) {
    // sqrt(13)*tanh(x), exp-based; correct limits at +-inf
    float e = __expf(2.0f * x);
    float r = __builtin_amdgcn_rcpf(e + 1.0f);
    return fmaf(-2.0f * SQRT13, r, SQRT13);
}

__device__ __forceinline__ float yeval(float xv, float a, float bb,
                                       float c0, float c1, float c2,
                                       float c3, float c4, float c5) {
    float t = tanh13(fmaf(xv, a, bb));
    float gg = __expf(-0.5f * t * t);
    float p = c5;
    p = fmaf(p, t, c4);
    p = fmaf(p, t, c3);
    p = fmaf(p, t, c2);
    p = fmaf(p, t, c1);
    p = fmaf(p, t, c0);
    return gg * p;
}

// Fused stats+cost, NO cross-block sync: block (b,c) reads all 8 rows of
// channel c itself (7 for stats only; own row kept in registers for the
// moment pass). Sibling blocks (b'=0..7, same c) are blockIdx = c + 64*b'
// -> same XCD (64 % 8 == 0) -> its L2 fetches the 8 rows once for all 8.
__global__ __launch_bounds__(512) void k_statcost(
        const float* __restrict__ x, const float* __restrict__ gamma,
        const float* __restrict__ beta, const float* __restrict__ Wt,
        float* __restrict__ pp, unsigned short* __restrict__ WtB) {
    int bc = blockIdx.x;
    int b  = bc >> 6;
    int c  = bc & 63;
    int tid = threadIdx.x;
    int lane = tid & 63, wid = tid >> 6;

    // one-time Wt -> bf16 (block 0; done before k_out launches)
    if (bc == 0)
        for (int i = tid; i < 4096; i += 512) WtB[i] = f2bf(Wt[i]);

    float s = 0.f, ss = 0.f;

    // 7 other rows of channel c: stats only (rolled loop, v[] reused)
    #pragma unroll 1
    for (int rr = 0; rr < 7; ++rr) {
        int bb = (b + 1 + rr) & 7;
        const float* xp = x + ((size_t)bb * NC + c) * NN;
        float4 v[8];
        #pragma unroll
        for (int i = 0; i < 8; ++i)
            v[i] = *(const float4*)(xp + i * 2048 + tid * 4);
        #pragma unroll
        for (int i = 0; i < 8; ++i) {
            s  += v[i].x + v[i].y + v[i].z + v[i].w;
            ss += v[i].x * v[i].x + v[i].y * v[i].y + v[i].z * v[i].z + v[i].w * v[i].w;
        }
    }

    // own row last: stats + keep in registers for the moment pass
    float4 keep[8];
    {
        const float* xp = x + ((size_t)b * NC + c) * NN;
        #pragma unroll
        for (int i = 0; i < 8; ++i)
            keep[i] = *(const float4*)(xp + i * 2048 + tid * 4);
        #pragma unroll
        for (int i = 0; i < 8; ++i) {
            s  += keep[i].x + keep[i].y + keep[i].z + keep[i].w;
            ss += keep[i].x * keep[i].x + keep[i].y * keep[i].y
                + keep[i].z * keep[i].z + keep[i].w * keep[i].w;
        }
    }

    // block-reduce stats; every thread forms (a, bsh) uniformly
    __shared__ float red2[2][8];
    for (int off = 32; off; off >>= 1) {
        s  += __shfl_down(s, off);
        ss += __shfl_down(ss, off);
    }
    if (lane == 0) { red2[0][wid] = s; red2[1][wid] = ss; }
    __syncthreads();
    float cs = 0.f, cq = 0.f;
    #pragma unroll
    for (int w2 = 0; w2 < 8; ++w2) { cs += red2[0][w2]; cq += red2[1][w2]; }
    const float inv = 1.0f / (float)(NB * NN);
    float mean = cs * inv;
    float var  = cq * inv - mean * mean;
    float istd = 1.0f / sqrtf(var + 1e-5f);
    float a   = gamma[c] * istd;
    float bsh = beta[c] - mean * a;

    // moments from registers (own row, no re-read)
    float m[6] = {0.f, 0.f, 0.f, 0.f, 0.f, 0.f};
    #pragma unroll
    for (int i = 0; i < 8; ++i) {
        float xs[4] = {keep[i].x, keep[i].y, keep[i].z, keep[i].w};
        #pragma unroll
        for (int j = 0; j < 4; ++j) {
            float xn = fmaf(xs[j], a, bsh);
            float t  = tanh13(xn);
            float g  = __expf(-0.5f * t * t);
            float u  = g * xn;
            m[0] += u;
            u *= t; m[1] += u;
            u *= t; m[2] += u;
            u *= t; m[3] += u;
            u *= t; m[4] += u;
            u *= t; m[5] += u;
        }
    }

    __shared__ float red6[6][8];
    #pragma unroll
    for (int k = 0; k < 6; ++k) {
        float vv = m[k];
        for (int off = 32; off; off >>= 1) vv += __shfl_down(vv, off);
        if (lane == 0) red6[k][wid] = vv;
    }
    __syncthreads();
    if (tid == 0) {
        float M[6];
        #pragma unroll
        for (int k = 0; k < 6; ++k) {
            float vv = 0.f;
            #pragma unroll
            for (int w2 = 0; w2 < 8; ++w2) vv += red6[k][w2];
            M[k] = vv;
        }

        // Hermite coeff matrix h[k][j]: psi_k = g * sum_j h[k][j] t^j
        float h[6][6];
        #pragma unroll
        for (int k = 0; k < 6; ++k)
            #pragma unroll
            for (int j = 0; j < 6; ++j) h[k][j] = 0.f;
        h[0][0] = 0.7511255444649425f;
        h[1][1] = 1.0622519320271969f;
        for (int k = 2; k < 6; ++k) {
            float s2 = sqrtf(2.0f / k), s1 = sqrtf((k - 1.0f) / k);
            for (int j = 5; j >= 0; --j) {
                float vv = (j > 0) ? s2 * h[k - 1][j - 1] : 0.f;
                h[k][j] = vv - s1 * h[k - 2][j];
            }
        }
        float cst[6], mx = -1e30f;
        #pragma unroll
        for (int k = 0; k < 6; ++k) {
            float vv = 0.f;
            #pragma unroll
            for (int j = 0; j < 6; ++j) vv += h[k][j] * M[j];
            cst[k] = vv;
            mx = fmaxf(mx, vv);
        }
        float sum = 0.f, w[6];
        #pragma unroll
        for (int k = 0; k < 6; ++k) { w[k] = expf(cst[k] - mx); sum += w[k]; }
        float r = 1.0f / sum;
        float* P = pp + (size_t)bc * 8;
        P[0] = a; P[1] = bsh;
        #pragma unroll
        for (int j = 0; j < 6; ++j) {
            float vv = 0.f;
            #pragma unroll
            for (int k = 0; k < 6; ++k) vv += w[k] * r * h[k][j];
            P[2 + j] = vv;
        }
    }
}

__global__ __launch_bounds__(256) void k_out(const float* __restrict__ x,
                                             const unsigned short* __restrict__ WtB,
                                             const float* __restrict__ bias,
                                             const float* __restrict__ pp,
                                             float* __restrict__ out) {
    __shared__ float ppl[512];  // SoA: ppl[f*64 + c]
    int tid  = threadIdx.x;
    int w    = tid >> 6;
    int l    = tid & 63;
    int grp  = l >> 4;
    int ln   = l & 15;
    int b    = blockIdx.x >> 6;
    int tile = blockIdx.x & 63;

    #pragma unroll
    for (int i0 = 0; i0 < 2; ++i0) {
        int i = i0 * 256 + tid;
        ppl[(i & 7) * 64 + (i >> 3)] = pp[(size_t)b * 512 + i];
    }
    __syncthreads();

    const float* xb = x + (size_t)b * NC * NN + tile * 256 + w * 64 + ln;

    // prefetch all x scalars this thread needs (64 regs)
    float xr[2][4][4][2];
    #pragma unroll
    for (int kk = 0; kk < 2; ++kk)
        #pragma unroll
        for (int q = 0; q < 4; ++q) {
            int c0 = kk * 32 + grp * 8 + 2 * q;
            const float* x0 = xb + (size_t)c0 * NN;
            const float* x1 = x0 + NN;
            #pragma unroll
            for (int nd = 0; nd < 4; ++nd) {
                xr[kk][q][nd][0] = x0[nd * 16];
                xr[kk][q][nd][1] = x1[nd * 16];
            }
        }

    // A fragments: Wt[o][c] bf16, a[j] = A[mo*16+ln][kk*32+grp*8+j]
    short8 af[2][4];
    #pragma unroll
    for (int kk = 0; kk < 2; ++kk)
        #pragma unroll
        for (int mo = 0; mo < 4; ++mo)
            af[kk][mo] = *reinterpret_cast<const short8*>(
                WtB + (mo * 16 + ln) * 64 + kk * 32 + grp * 8);

    // bias values this thread stores: o = mo*16 + grp*4 + r
    float4 bias4[4];
    #pragma unroll
    for (int mo = 0; mo < 4; ++mo)
        bias4[mo] = *(const float4*)(bias + mo * 16 + grp * 4);

    f32x4 acc[4][4];
    #pragma unroll
    for (int mo = 0; mo < 4; ++mo)
        #pragma unroll
        for (int nd = 0; nd < 4; ++nd)
            acc[mo][nd] = (f32x4){0.f, 0.f, 0.f, 0.f};

    #pragma unroll
    for (int kk = 0; kk < 2; ++kk) {
        unsigned int bu[4][4];  // [nd][q]
        #pragma unroll
        for (int q = 0; q < 4; ++q) {
            int c0 = kk * 32 + grp * 8 + 2 * q;
            // adjacent-channel params -> ds_read_b64
            float2 A2 = *(const float2*)&ppl[c0];
            float2 B2 = *(const float2*)&ppl[64 + c0];
            float2 P0 = *(const float2*)&ppl[128 + c0];
            float2 P1 = *(const float2*)&ppl[192 + c0];
            float2 P2 = *(const float2*)&ppl[256 + c0];
            float2 P3 = *(const float2*)&ppl[320 + c0];
            float2 P4 = *(const float2*)&ppl[384 + c0];
            float2 P5 = *(const float2*)&ppl[448 + c0];
            #pragma unroll
            for (int nd = 0; nd < 4; ++nd) {
                float y0 = yeval(xr[kk][q][nd][0], A2.x, B2.x, P0.x, P1.x, P2.x, P3.x, P4.x, P5.x);
                float y1 = yeval(xr[kk][q][nd][1], A2.y, B2.y, P0.y, P1.y, P2.y, P3.y, P4.y, P5.y);
                bu[nd][q] = pack_bf2(y0, y1);
            }
        }
        #pragma unroll
        for (int nd = 0; nd < 4; ++nd) {
            union { unsigned int u[4]; short8 s; } U;
            U.u[0] = bu[nd][0]; U.u[1] = bu[nd][1];
            U.u[2] = bu[nd][2]; U.u[3] = bu[nd][3];
            #pragma unroll
            for (int mo = 0; mo < 4; ++mo)
                acc[mo][nd] = __builtin_amdgcn_mfma_f32_16x16x32_bf16(
                    af[kk][mo], U.s, acc[mo][nd], 0, 0, 0);
        }
    }

    // epilogue: C/D layout col=lane&15, row=(lane>>4)*4+reg (m89-verified)
    float* ob = out + (size_t)b * NO * NN + tile * 256 + w * 64 + ln;
    #pragma unroll
    for (int mo = 0; mo < 4; ++mo) {
        #pragma unroll
        for (int nd = 0; nd < 4; ++nd) {
            f32x4 v = acc[mo][nd];
            ob[(size_t)(mo * 16 + grp * 4 + 0) * NN + nd * 16] = v[0] + bias4[mo].x;
            ob[(size_t)(mo * 16 + grp * 4 + 1) * NN + nd * 16] = v[1] + bias4[mo].y;
            ob[(size_t)(mo * 16 + grp * 4 + 2) * NN + nd * 16] = v[2] + bias4[mo].z;
            ob[(size_t)(mo * 16 + grp * 4 + 3) * NN + nd * 16] = v[3] + bias4[mo].w;
        }
    }
}

extern "C" void kernel_launch(void* const* d_in, const int* in_sizes, int n_in,
                              void* d_out, int out_size, void* d_ws, size_t ws_size,
                              hipStream_t stream) {
    const float* x     = (const float*)d_in[0];
    const float* gamma = (const float*)d_in[1];
    const float* beta  = (const float*)d_in[2];
    const float* Wt    = (const float*)d_in[3];
    const float* bias  = (const float*)d_in[4];
    float* out = (float*)d_out;
    float* ws  = (float*)d_ws;

    float* pp = ws;                                      // 4096 floats
    unsigned short* WtB = (unsigned short*)(ws + 4096);  // 4096 ushorts

    k_statcost<<<dim3(NB * NC), dim3(512), 0, stream>>>(x, gamma, beta, Wt, pp, WtB);
    k_out<<<dim3(NB * NC), dim3(256), 0, stream>>>(x, WtB, bias, pp, out);
}

// Round 16
// 35.737 us; speedup vs baseline: 1.0944x; 1.0944x over previous
//
#include <hip/hip_runtime.h>

typedef short short8 __attribute__((ext_vector_type(8)));
typedef float f32x4 __attribute__((ext_vector_type(4)));

#define NB 8
#define NC 64
#define NN 16384
#define NO 64
#define SQRT13 3.605551275463989f

// ws layout (floats):
// [0, 1024)     : partial (sum,sumsq) per (b,c)                 512*2
// [1024, 5120)  : pp[b][c][8] = {a, bsh, cp0..cp5}              512*8
// [5120, 7168)  : WtB bf16[o][c] row-major (4096 ushort = 8KB)

__device__ __forceinline__ unsigned short f2bf(float f) {
    unsigned int u = __builtin_bit_cast(unsigned int, f);
    u += 0x7fffu + ((u >> 16) & 1u);   // RNE
    return (unsigned short)(u >> 16);
}

__device__ __forceinline__ unsigned int pack_bf2(float lo, float hi) {
    return (unsigned int)f2bf(lo) | ((unsigned int)f2bf(hi) << 16);
}

__device__ __forceinline__ float tanh13(float x) {
    // sqrt(13)*tanh(x), exp-based; correct limits at +-inf
    float e = __expf(2.0f * x);
    float r = __builtin_amdgcn_rcpf(e + 1.0f);
    return fmaf(-2.0f * SQRT13, r, SQRT13);
}

__device__ __forceinline__ float yeval(float xv, float a, float bb,
                                       float c0, float c1, float c2,
                                       float c3, float c4, float c5) {
    float t = tanh13(fmaf(xv, a, bb));
    float gg = __expf(-0.5f * t * t);
    float p = c5;
    p = fmaf(p, t, c4);
    p = fmaf(p, t, c3);
    p = fmaf(p, t, c2);
    p = fmaf(p, t, c1);
    p = fmaf(p, t, c0);
    return gg * p;
}

__global__ __launch_bounds__(256) void k_stats(const float* __restrict__ x,
                                               float* __restrict__ part,
                                               const float* __restrict__ Wt,
                                               unsigned short* __restrict__ WtB) {
    int bc = blockIdx.x;
    const float* xp = x + (size_t)bc * NN;
    int tid = threadIdx.x;
    float s = 0.f, ss = 0.f;
    #pragma unroll
    for (int i = 0; i < 16; ++i) {
        float4 v = *(const float4*)(xp + i * 1024 + tid * 4);
        s  += v.x + v.y + v.z + v.w;
        ss += v.x * v.x + v.y * v.y + v.z * v.z + v.w * v.w;
    }
    for (int off = 32; off; off >>= 1) {
        s  += __shfl_down(s, off);
        ss += __shfl_down(ss, off);
    }
    __shared__ float red[2][4];
    int lane = tid & 63, wid = tid >> 6;
    if (lane == 0) { red[0][wid] = s; red[1][wid] = ss; }
    __syncthreads();
    if (tid == 0) {
        part[bc * 2 + 0] = red[0][0] + red[0][1] + red[0][2] + red[0][3];
        part[bc * 2 + 1] = red[1][0] + red[1][1] + red[1][2] + red[1][3];
    }
    if (bc == 0)
        for (int i = tid; i < 4096; i += 256) WtB[i] = f2bf(Wt[i]);
}

__global__ __launch_bounds__(256) void k_cost(const float* __restrict__ x,
                                              const float* __restrict__ part,
                                              const float* __restrict__ gamma,
                                              const float* __restrict__ beta,
                                              float* __restrict__ pp) {
    // L2-affinity + LRU-friendly row order: keep XCD (bc%8), but walk rows
    // in REVERSE within each XCD so k_cost reads the rows k_stats cached
    // most recently first (k_stats's 64 rows/XCD exactly fill 4MB L2).
    int bc = (blockIdx.x & 7) | ((63 - (blockIdx.x >> 3)) << 3);
    int c  = bc & 63;
    int tid = threadIdx.x;

    float s = 0.f, ss = 0.f;
    #pragma unroll
    for (int bb = 0; bb < NB; ++bb) {
        s  += part[(bb * NC + c) * 2 + 0];
        ss += part[(bb * NC + c) * 2 + 1];
    }
    const float inv = 1.0f / (float)(NB * NN);
    float mean = s * inv;
    float var  = ss * inv - mean * mean;
    float istd = 1.0f / sqrtf(var + 1e-5f);
    float a   = gamma[c] * istd;
    float bsh = beta[c] - mean * a;

    const float* xp = x + (size_t)bc * NN;
    float m[6] = {0.f, 0.f, 0.f, 0.f, 0.f, 0.f};

    // two half-tiles: load 8 float4 up-front (32 VGPR), then compute.
    #pragma unroll
    for (int half = 0; half < 2; ++half) {
        float4 v[8];
        #pragma unroll
        for (int i = 0; i < 8; ++i)
            v[i] = *(const float4*)(xp + (half * 8 + i) * 1024 + tid * 4);
        #pragma unroll
        for (int i = 0; i < 8; ++i) {
            float xs[4] = {v[i].x, v[i].y, v[i].z, v[i].w};
            #pragma unroll
            for (int j = 0; j < 4; ++j) {
                float xn = fmaf(xs[j], a, bsh);
                float t  = tanh13(xn);
                float g  = __expf(-0.5f * t * t);
                float u  = g * xn;
                m[0] += u;
                u *= t; m[1] += u;
                u *= t; m[2] += u;
                u *= t; m[3] += u;
                u *= t; m[4] += u;
                u *= t; m[5] += u;
            }
        }
    }

    __shared__ float red6[6][4];
    int lane = tid & 63, wid = tid >> 6;
    #pragma unroll
    for (int k = 0; k < 6; ++k) {
        float v = m[k];
        for (int off = 32; off; off >>= 1) v += __shfl_down(v, off);
        if (lane == 0) red6[k][wid] = v;
    }
    __syncthreads();
    if (tid == 0) {
        float M[6];
        #pragma unroll
        for (int k = 0; k < 6; ++k)
            M[k] = red6[k][0] + red6[k][1] + red6[k][2] + red6[k][3];

        // Hermite coeff matrix h[k][j]: psi_k = g * sum_j h[k][j] t^j
        float h[6][6];
        #pragma unroll
        for (int k = 0; k < 6; ++k)
            #pragma unroll
            for (int j = 0; j < 6; ++j) h[k][j] = 0.f;
        h[0][0] = 0.7511255444649425f;
        h[1][1] = 1.0622519320271969f;
        for (int k = 2; k < 6; ++k) {
            float s2 = sqrtf(2.0f / k), s1 = sqrtf((k - 1.0f) / k);
            for (int j = 5; j >= 0; --j) {
                float v = (j > 0) ? s2 * h[k - 1][j - 1] : 0.f;
                h[k][j] = v - s1 * h[k - 2][j];
            }
        }
        float cst[6], mx = -1e30f;
        #pragma unroll
        for (int k = 0; k < 6; ++k) {
            float v = 0.f;
            #pragma unroll
            for (int j = 0; j < 6; ++j) v += h[k][j] * M[j];
            cst[k] = v;
            mx = fmaxf(mx, v);
        }
        float sum = 0.f, w[6];
        #pragma unroll
        for (int k = 0; k < 6; ++k) { w[k] = expf(cst[k] - mx); sum += w[k]; }
        float r = 1.0f / sum;
        float* P = pp + (size_t)bc * 8;
        P[0] = a; P[1] = bsh;
        #pragma unroll
        for (int j = 0; j < 6; ++j) {
            float v = 0.f;
            #pragma unroll
            for (int k = 0; k < 6; ++k) v += w[k] * r * h[k][j];
            P[2 + j] = v;
        }
    }
}

__global__ __launch_bounds__(256) void k_out(const float* __restrict__ x,
                                             const unsigned short* __restrict__ WtB,
                                             const float* __restrict__ bias,
                                             const float* __restrict__ pp,
                                             float* __restrict__ out) {
    __shared__ float ppl[512];  // SoA: ppl[f*64 + c]
    int tid  = threadIdx.x;
    int w    = tid >> 6;
    int l    = tid & 63;
    int grp  = l >> 4;
    int ln   = l & 15;
    int b    = blockIdx.x >> 6;
    int tile = blockIdx.x & 63;

    #pragma unroll
    for (int i0 = 0; i0 < 2; ++i0) {
        int i = i0 * 256 + tid;
        ppl[(i & 7) * 64 + (i >> 3)] = pp[(size_t)b * 512 + i];
    }
    __syncthreads();

    // A fragments: Wt[o][c] bf16, a[j] = A[mo*16+ln][kk*32+grp*8+j]
    short8 af[2][4];
    #pragma unroll
    for (int kk = 0; kk < 2; ++kk)
        #pragma unroll
        for (int mo = 0; mo < 4; ++mo)
            af[kk][mo] = *reinterpret_cast<const short8*>(
                WtB + (mo * 16 + ln) * 64 + kk * 32 + grp * 8);

    // bias values this thread stores: o = mo*16 + grp*4 + r
    float4 bias4[4];
    #pragma unroll
    for (int mo = 0; mo < 4; ++mo)
        bias4[mo] = *(const float4*)(bias + mo * 16 + grp * 4);

    f32x4 acc[4][4];
    #pragma unroll
    for (int mo = 0; mo < 4; ++mo)
        #pragma unroll
        for (int nd = 0; nd < 4; ++nd)
            acc[mo][nd] = (f32x4){0.f, 0.f, 0.f, 0.f};

    const float* xb = x + (size_t)b * NC * NN + tile * 256 + w * 64 + ln;

    #pragma unroll
    for (int kk = 0; kk < 2; ++kk) {
        unsigned int bu[4][4];  // [nd][q]
        #pragma unroll
        for (int q = 0; q < 4; ++q) {
            int c0 = kk * 32 + grp * 8 + 2 * q;
            // adjacent-channel params -> ds_read_b64
            float2 A2 = *(const float2*)&ppl[c0];
            float2 B2 = *(const float2*)&ppl[64 + c0];
            float2 P0 = *(const float2*)&ppl[128 + c0];
            float2 P1 = *(const float2*)&ppl[192 + c0];
            float2 P2 = *(const float2*)&ppl[256 + c0];
            float2 P3 = *(const float2*)&ppl[320 + c0];
            float2 P4 = *(const float2*)&ppl[384 + c0];
            float2 P5 = *(const float2*)&ppl[448 + c0];
            const float* xc0 = xb + (size_t)c0 * NN;
            const float* xc1 = xc0 + NN;
            #pragma unroll
            for (int nd = 0; nd < 4; ++nd) {
                float y0 = yeval(xc0[nd * 16], A2.x, B2.x, P0.x, P1.x, P2.x, P3.x, P4.x, P5.x);
                float y1 = yeval(xc1[nd * 16], A2.y, B2.y, P0.y, P1.y, P2.y, P3.y, P4.y, P5.y);
                bu[nd][q] = pack_bf2(y0, y1);
            }
        }
        #pragma unroll
        for (int nd = 0; nd < 4; ++nd) {
            union { unsigned int u[4]; short8 s; } U;
            U.u[0] = bu[nd][0]; U.u[1] = bu[nd][1];
            U.u[2] = bu[nd][2]; U.u[3] = bu[nd][3];
            #pragma unroll
            for (int mo = 0; mo < 4; ++mo)
                acc[mo][nd] = __builtin_amdgcn_mfma_f32_16x16x32_bf16(
                    af[kk][mo], U.s, acc[mo][nd], 0, 0, 0);
        }
    }

    // epilogue: C/D layout col=lane&15, row=(lane>>4)*4+reg (m89-verified)
    float* ob = out + (size_t)b * NO * NN + tile * 256 + w * 64 + ln;
    #pragma unroll
    for (int mo = 0; mo < 4; ++mo) {
        #pragma unroll
        for (int nd = 0; nd < 4; ++nd) {
            f32x4 v = acc[mo][nd];
            ob[(size_t)(mo * 16 + grp * 4 + 0) * NN + nd * 16] = v[0] + bias4[mo].x;
            ob[(size_t)(mo * 16 + grp * 4 + 1) * NN + nd * 16] = v[1] + bias4[mo].y;
            ob[(size_t)(mo * 16 + grp * 4 + 2) * NN + nd * 16] = v[2] + bias4[mo].z;
            ob[(size_t)(mo * 16 + grp * 4 + 3) * NN + nd * 16] = v[3] + bias4[mo].w;
        }
    }
}

extern "C" void kernel_launch(void* const* d_in, const int* in_sizes, int n_in,
                              void* d_out, int out_size, void* d_ws, size_t ws_size,
                              hipStream_t stream) {
    const float* x     = (const float*)d_in[0];
    const float* gamma = (const float*)d_in[1];
    const float* beta  = (const float*)d_in[2];
    const float* Wt    = (const float*)d_in[3];
    const float* bias  = (const float*)d_in[4];
    float* out = (float*)d_out;
    float* ws  = (float*)d_ws;

    float* part = ws;                                    // 1024 floats
    float* pp   = ws + 1024;                             // 4096 floats
    unsigned short* WtB = (unsigned short*)(ws + 5120);  // 4096 ushorts

    k_stats<<<dim3(NB * NC), dim3(256), 0, stream>>>(x, part, Wt, WtB);
    k_cost<<<dim3(NB * NC), dim3(256), 0, stream>>>(x, part, gamma, beta, pp);
    k_out<<<dim3(NB * NC), dim3(256), 0, stream>>>(x, WtB, bias, pp, out);
}